// Round 1
// baseline (464.456 us; speedup 1.0000x reference)
//
#include <hip/hip_runtime.h>
#include <stdint.h>

// GCN layer: out = prelu(W @ segsum(A_val * h[A_col] -> A_row) + b, act_a)
//            h   = prelu(Wr @ AX + br, g_a)
// Strategy: f16 MFMA GEMMs (fused fp32->f16 staging), on-device CSR build,
// gather-SpMM (one wave per destination row, fp32 register accum, no fp32 atomics).

typedef _Float16 half8 __attribute__((ext_vector_type(8)));
typedef _Float16 half4 __attribute__((ext_vector_type(4)));
typedef _Float16 half2v __attribute__((ext_vector_type(2)));
typedef float floatx4 __attribute__((ext_vector_type(4)));

#define LDK 136  // LDS row stride in halfs: 128 + 8 (16B pad -> 2-way-max bank groups on b128 reads)

// ---------------- GEMM: out = prelu(X @ W^T + b) ----------------
// X: [N,128] (fp32 or f16), W: [128,128] fp32 row-major, out[i][c] = dot(X[i,:], W[c,:])
// 128x128x128 tile per block, 256 threads (4 waves), f16 MFMA 16x16x32.
template<bool IN_F32, bool OUT_F16>
__global__ __launch_bounds__(256, 2)
void gemm128_prelu(const void* __restrict__ Xv, const float* __restrict__ W,
                   const float* __restrict__ bias, const float* __restrict__ alpha_p,
                   void* __restrict__ outv, int N)
{
    __shared__ _Float16 Xs[128 * LDK];
    __shared__ _Float16 Ws[128 * LDK];
    const int tid = threadIdx.x;
    const int bm  = blockIdx.x * 128;
    const float alpha = *alpha_p;

    // stage W fp32->f16: 128x128 floats = 4096 float4-chunks, 16 per thread
#pragma unroll
    for (int i = 0; i < 16; ++i) {
        int c   = tid + i * 256;
        int row = c >> 5;           // 32 chunks per row
        int coff = (c & 31) * 4;    // element offset
        float4 f = *(const float4*)(W + row * 128 + coff);
        half4 hv = { (_Float16)f.x, (_Float16)f.y, (_Float16)f.z, (_Float16)f.w };
        *(half4*)(&Ws[row * LDK + coff]) = hv;
    }
    // stage X tile
    if (IN_F32) {
        const float* X = (const float*)Xv;
#pragma unroll
        for (int i = 0; i < 16; ++i) {
            int c   = tid + i * 256;
            int row = c >> 5;
            int coff = (c & 31) * 4;
            int grow = bm + row;
            half4 hv = {};
            if (grow < N) {
                float4 f = *(const float4*)(X + (size_t)grow * 128 + coff);
                hv[0] = (_Float16)f.x; hv[1] = (_Float16)f.y;
                hv[2] = (_Float16)f.z; hv[3] = (_Float16)f.w;
            }
            *(half4*)(&Xs[row * LDK + coff]) = hv;
        }
    } else {
        const _Float16* X = (const _Float16*)Xv;
#pragma unroll
        for (int i = 0; i < 8; ++i) {
            int c   = tid + i * 256;
            int row = c >> 4;          // 16 chunks (of 8 halfs) per row
            int coff = (c & 15) * 8;
            int grow = bm + row;
            half8 hv = {};
            if (grow < N) hv = *(const half8*)(X + (size_t)grow * 128 + coff);
            *(half8*)(&Xs[row * LDK + coff]) = hv;
        }
    }
    __syncthreads();

    const int wave = tid >> 6;     // 0..3 -> rows [wave*32, wave*32+32)
    const int lane = tid & 63;
    const int l15  = lane & 15;
    const int quad = lane >> 4;

    floatx4 acc[2][8] = {};        // 2 M-tiles x 8 N-tiles x 4 regs
#pragma unroll
    for (int k0 = 0; k0 < 128; k0 += 32) {
        // A frags: lane holds A[m=l15][k=quad*8+j]
        half8 a0 = *(const half8*)(&Xs[(wave * 32 +      l15) * LDK + k0 + quad * 8]);
        half8 a1 = *(const half8*)(&Xs[(wave * 32 + 16 + l15) * LDK + k0 + quad * 8]);
        half8 b[8];
#pragma unroll
        for (int n = 0; n < 8; ++n)   // B frags: lane holds B[k=quad*8+j][n=l15] = W[n16+l15][k]
            b[n] = *(const half8*)(&Ws[(n * 16 + l15) * LDK + k0 + quad * 8]);
#pragma unroll
        for (int n = 0; n < 8; ++n) {
            acc[0][n] = __builtin_amdgcn_mfma_f32_16x16x32_f16(a0, b[n], acc[0][n], 0, 0, 0);
            acc[1][n] = __builtin_amdgcn_mfma_f32_16x16x32_f16(a1, b[n], acc[1][n], 0, 0, 0);
        }
    }

    // epilogue: D[m=quad*4+r][n=l15]
#pragma unroll
    for (int mt = 0; mt < 2; ++mt) {
#pragma unroll
        for (int n = 0; n < 8; ++n) {
#pragma unroll
            for (int r = 0; r < 4; ++r) {
                int row = bm + wave * 32 + mt * 16 + quad * 4 + r;
                int col = n * 16 + l15;
                if (row < N) {
                    float v = acc[mt][n][r] + bias[col];
                    v = (v >= 0.f) ? v : alpha * v;
                    if (OUT_F16) ((_Float16*)outv)[(size_t)row * 128 + col] = (_Float16)v;
                    else         ((float*)outv)[(size_t)row * 128 + col]    = v;
                }
            }
        }
    }
}

// ---------------- CSR build ----------------
__global__ void hist_kernel(const int* __restrict__ rows, int* __restrict__ cnt, int E)
{
    int i = blockIdx.x * blockDim.x + threadIdx.x;
    if (i < E) atomicAdd(&cnt[rows[i]], 1);
}

// per-1024-chunk block sums
__global__ void scan_block_sums(const int* __restrict__ cnt, int* __restrict__ bsum, int N)
{
    __shared__ int sd[256];
    int b = blockIdx.x, t = threadIdx.x;
    int base = b * 1024;
    int s = 0;
#pragma unroll
    for (int j = 0; j < 4; ++j) {
        int idx = base + t * 4 + j;
        if (idx < N) s += cnt[idx];
    }
    sd[t] = s;
    __syncthreads();
    for (int off = 128; off > 0; off >>= 1) {
        if (t < off) sd[t] += sd[t + off];
        __syncthreads();
    }
    if (t == 0) bsum[b] = sd[0];
}

// serial exclusive scan of ~98 block sums (trivial)
__global__ void scan_offsets(int* __restrict__ bsum, int nb)
{
    if (blockIdx.x == 0 && threadIdx.x == 0) {
        int acc = 0;
        for (int i = 0; i < nb; ++i) { int v = bsum[i]; bsum[i] = acc; acc += v; }
    }
}

// write row_ptr + cursor (exclusive prefix within chunk + chunk offset)
__global__ void scan_write(const int* __restrict__ cnt, const int* __restrict__ bsum,
                           int* __restrict__ row_ptr, int* __restrict__ cursor, int N, int E)
{
    __shared__ int sd[256];
    int b = blockIdx.x, t = threadIdx.x;
    int base = b * 1024;
    int v[4]; int s = 0;
#pragma unroll
    for (int j = 0; j < 4; ++j) {
        int idx = base + t * 4 + j;
        v[j] = (idx < N) ? cnt[idx] : 0;
        s += v[j];
    }
    sd[t] = s;
    __syncthreads();
    for (int off = 1; off < 256; off <<= 1) {  // Hillis-Steele inclusive
        int x = (t >= off) ? sd[t - off] : 0;
        __syncthreads();
        sd[t] += x;
        __syncthreads();
    }
    int off0 = bsum[b] + ((t == 0) ? 0 : sd[t - 1]);
#pragma unroll
    for (int j = 0; j < 4; ++j) {
        int idx = base + t * 4 + j;
        if (idx < N) { row_ptr[idx] = off0; cursor[idx] = off0; off0 += v[j]; }
    }
    if (b == 0 && t == 0) row_ptr[N] = E;
}

__global__ void scatter_kernel(const int* __restrict__ rows, const int* __restrict__ cols,
                               const float* __restrict__ vals, int* __restrict__ cursor,
                               int* __restrict__ col_s, float* __restrict__ val_s, int E)
{
    int i = blockIdx.x * blockDim.x + threadIdx.x;
    if (i < E) {
        int r = rows[i];
        int p = atomicAdd(&cursor[r], 1);
        col_s[p] = cols[i];
        val_s[p] = vals[i];
    }
}

// ---------------- gather SpMM ----------------
// one wave per destination row; lane holds 2 columns; fp32 accum; temp written f16
__global__ __launch_bounds__(256)
void spmm_gather(const int* __restrict__ row_ptr, const int* __restrict__ col_s,
                 const float* __restrict__ val_s, const _Float16* __restrict__ h,
                 _Float16* __restrict__ temp, int N)
{
    int wave = threadIdx.x >> 6;
    int lane = threadIdx.x & 63;
    int row  = blockIdx.x * 4 + wave;
    if (row >= N) return;
    int s = row_ptr[row], e = row_ptr[row + 1];
    float acc0 = 0.f, acc1 = 0.f;
    int i = s;
    for (; i + 1 < e; i += 2) {  // 2-edge unroll for load-latency overlap
        int   c0 = col_s[i],     c1 = col_s[i + 1];
        float a0 = val_s[i],     a1 = val_s[i + 1];
        half2v v0 = *(const half2v*)(h + (size_t)c0 * 128 + lane * 2);
        half2v v1 = *(const half2v*)(h + (size_t)c1 * 128 + lane * 2);
        acc0 += a0 * (float)v0[0]; acc1 += a0 * (float)v0[1];
        acc0 += a1 * (float)v1[0]; acc1 += a1 * (float)v1[1];
    }
    if (i < e) {
        int c = col_s[i]; float a = val_s[i];
        half2v v = *(const half2v*)(h + (size_t)c * 128 + lane * 2);
        acc0 += a * (float)v[0]; acc1 += a * (float)v[1];
    }
    half2v o = { (_Float16)acc0, (_Float16)acc1 };
    *(half2v*)(temp + (size_t)row * 128 + lane * 2) = o;
}

// ---------------- launcher ----------------
static inline size_t align256(size_t x) { return (x + 255) & ~(size_t)255; }

extern "C" void kernel_launch(void* const* d_in, const int* in_sizes, int n_in,
                              void* d_out, int out_size, void* d_ws, size_t ws_size,
                              hipStream_t stream)
{
    const float* AX        = (const float*)d_in[0];
    const int*   A_row     = (const int*)  d_in[1];
    const int*   A_col     = (const int*)  d_in[2];
    const float* A_val     = (const float*)d_in[3];
    const float* Wr_w      = (const float*)d_in[4];
    const float* Wr_b      = (const float*)d_in[5];
    const float* W_w       = (const float*)d_in[6];
    const float* W_b       = (const float*)d_in[7];
    const float* g_alpha   = (const float*)d_in[8];
    const float* act_alpha = (const float*)d_in[9];

    const int N = in_sizes[0] / 128;
    const int E = in_sizes[1];

    // workspace layout (~65.3 MB)
    char* ws = (char*)d_ws;
    size_t off = 0;
    _Float16* h      = (_Float16*)(ws + off); off += align256((size_t)N * 128 * 2);
    _Float16* temp   = (_Float16*)(ws + off); off += align256((size_t)N * 128 * 2);
    int*      col_s  = (int*)     (ws + off); off += align256((size_t)E * 4);
    float*    val_s  = (float*)   (ws + off); off += align256((size_t)E * 4);
    int*      cnt    = (int*)     (ws + off); off += align256((size_t)N * 4);
    int*      cursor = (int*)     (ws + off); off += align256((size_t)N * 4);
    int*      row_ptr= (int*)     (ws + off); off += align256((size_t)(N + 1) * 4);
    int*      bsum   = (int*)     (ws + off); off += align256(1024 * 4);
    (void)ws_size; (void)n_in; (void)out_size;

    const int gemm_grid = (N + 127) / 128;
    const int nb        = (N + 1023) / 1024;

    // h = prelu(AX @ Wr^T + br)   [writes f16]
    gemm128_prelu<true, true><<<gemm_grid, 256, 0, stream>>>(AX, Wr_w, Wr_b, g_alpha, h, N);

    // CSR build
    hipMemsetAsync(cnt, 0, (size_t)N * 4, stream);
    hist_kernel<<<(E + 255) / 256, 256, 0, stream>>>(A_row, cnt, E);
    scan_block_sums<<<nb, 256, 0, stream>>>(cnt, bsum, N);
    scan_offsets<<<1, 64, 0, stream>>>(bsum, nb);
    scan_write<<<nb, 256, 0, stream>>>(cnt, bsum, row_ptr, cursor, N, E);
    scatter_kernel<<<(E + 255) / 256, 256, 0, stream>>>(A_row, A_col, A_val, cursor, col_s, val_s, E);

    // temp[i] = sum_e val * h[col]   [writes f16]
    spmm_gather<<<(N + 3) / 4, 256, 0, stream>>>(row_ptr, col_s, val_s, h, temp, N);

    // out = prelu(temp @ W^T + b)   [writes fp32]
    gemm128_prelu<false, false><<<gemm_grid, 256, 0, stream>>>(temp, W_w, W_b, act_alpha, d_out, N);
}

// Round 2
// 426.852 us; speedup vs baseline: 1.0881x; 1.0881x over previous
//
#include <hip/hip_runtime.h>
#include <stdint.h>

// GCN layer: out = prelu(W @ segsum(A_val * h[A_col] -> A_row) + b, act_a)
//            h   = prelu(Wr @ AX + br, g_a)
// Strategy: f16 MFMA GEMMs (fused fp32->f16 staging), on-device CSR build
// with PACKED (col,val) 8B scatter (R1: two 4B scatters to separate arrays
// gave 153MB WRITE_SIZE = 12x amplification; packing halves random lines),
// gather-SpMM (one wave per destination row, fp32 register accum).

typedef _Float16 half8 __attribute__((ext_vector_type(8)));
typedef _Float16 half4 __attribute__((ext_vector_type(4)));
typedef _Float16 half2v __attribute__((ext_vector_type(2)));
typedef float floatx4 __attribute__((ext_vector_type(4)));

#define LDK 136  // LDS row stride in halfs: 128 + 8

// ---------------- GEMM: out = prelu(X @ W^T + b) ----------------
template<bool IN_F32, bool OUT_F16>
__global__ __launch_bounds__(256, 2)
void gemm128_prelu(const void* __restrict__ Xv, const float* __restrict__ W,
                   const float* __restrict__ bias, const float* __restrict__ alpha_p,
                   void* __restrict__ outv, int N)
{
    __shared__ _Float16 Xs[128 * LDK];
    __shared__ _Float16 Ws[128 * LDK];
    const int tid = threadIdx.x;
    const int bm  = blockIdx.x * 128;
    const float alpha = *alpha_p;

#pragma unroll
    for (int i = 0; i < 16; ++i) {
        int c   = tid + i * 256;
        int row = c >> 5;
        int coff = (c & 31) * 4;
        float4 f = *(const float4*)(W + row * 128 + coff);
        half4 hv = { (_Float16)f.x, (_Float16)f.y, (_Float16)f.z, (_Float16)f.w };
        *(half4*)(&Ws[row * LDK + coff]) = hv;
    }
    if (IN_F32) {
        const float* X = (const float*)Xv;
#pragma unroll
        for (int i = 0; i < 16; ++i) {
            int c   = tid + i * 256;
            int row = c >> 5;
            int coff = (c & 31) * 4;
            int grow = bm + row;
            half4 hv = {};
            if (grow < N) {
                float4 f = *(const float4*)(X + (size_t)grow * 128 + coff);
                hv[0] = (_Float16)f.x; hv[1] = (_Float16)f.y;
                hv[2] = (_Float16)f.z; hv[3] = (_Float16)f.w;
            }
            *(half4*)(&Xs[row * LDK + coff]) = hv;
        }
    } else {
        const _Float16* X = (const _Float16*)Xv;
#pragma unroll
        for (int i = 0; i < 8; ++i) {
            int c   = tid + i * 256;
            int row = c >> 4;
            int coff = (c & 15) * 8;
            int grow = bm + row;
            half8 hv = {};
            if (grow < N) hv = *(const half8*)(X + (size_t)grow * 128 + coff);
            *(half8*)(&Xs[row * LDK + coff]) = hv;
        }
    }
    __syncthreads();

    const int wave = tid >> 6;
    const int lane = tid & 63;
    const int l15  = lane & 15;
    const int quad = lane >> 4;

    floatx4 acc[2][8] = {};
#pragma unroll
    for (int k0 = 0; k0 < 128; k0 += 32) {
        half8 a0 = *(const half8*)(&Xs[(wave * 32 +      l15) * LDK + k0 + quad * 8]);
        half8 a1 = *(const half8*)(&Xs[(wave * 32 + 16 + l15) * LDK + k0 + quad * 8]);
        half8 b[8];
#pragma unroll
        for (int n = 0; n < 8; ++n)
            b[n] = *(const half8*)(&Ws[(n * 16 + l15) * LDK + k0 + quad * 8]);
#pragma unroll
        for (int n = 0; n < 8; ++n) {
            acc[0][n] = __builtin_amdgcn_mfma_f32_16x16x32_f16(a0, b[n], acc[0][n], 0, 0, 0);
            acc[1][n] = __builtin_amdgcn_mfma_f32_16x16x32_f16(a1, b[n], acc[1][n], 0, 0, 0);
        }
    }

#pragma unroll
    for (int mt = 0; mt < 2; ++mt) {
#pragma unroll
        for (int n = 0; n < 8; ++n) {
#pragma unroll
            for (int r = 0; r < 4; ++r) {
                int row = bm + wave * 32 + mt * 16 + quad * 4 + r;
                int col = n * 16 + l15;
                if (row < N) {
                    float v = acc[mt][n][r] + bias[col];
                    v = (v >= 0.f) ? v : alpha * v;
                    if (OUT_F16) ((_Float16*)outv)[(size_t)row * 128 + col] = (_Float16)v;
                    else         ((float*)outv)[(size_t)row * 128 + col]    = v;
                }
            }
        }
    }
}

// ---------------- CSR build ----------------
__global__ void hist_kernel(const int* __restrict__ rows, int* __restrict__ cnt, int E)
{
    int i = blockIdx.x * blockDim.x + threadIdx.x;
    if (i < E) atomicAdd(&cnt[rows[i]], 1);
}

__global__ void scan_block_sums(const int* __restrict__ cnt, int* __restrict__ bsum, int N)
{
    __shared__ int sd[256];
    int b = blockIdx.x, t = threadIdx.x;
    int base = b * 1024;
    int s = 0;
#pragma unroll
    for (int j = 0; j < 4; ++j) {
        int idx = base + t * 4 + j;
        if (idx < N) s += cnt[idx];
    }
    sd[t] = s;
    __syncthreads();
    for (int off = 128; off > 0; off >>= 1) {
        if (t < off) sd[t] += sd[t + off];
        __syncthreads();
    }
    if (t == 0) bsum[b] = sd[0];
}

// parallel exclusive scan of block sums (nb <= 128), single block of 128
__global__ void scan_offsets(int* __restrict__ bsum, int nb)
{
    __shared__ int sd[128];
    int t = threadIdx.x;
    sd[t] = (t < nb) ? bsum[t] : 0;
    __syncthreads();
    for (int off = 1; off < 128; off <<= 1) {
        int x = (t >= off) ? sd[t - off] : 0;
        __syncthreads();
        sd[t] += x;
        __syncthreads();
    }
    if (t < nb) bsum[t] = (t == 0) ? 0 : sd[t - 1];
}

__global__ void scan_write(const int* __restrict__ cnt, const int* __restrict__ bsum,
                           int* __restrict__ row_ptr, int* __restrict__ cursor, int N, int E)
{
    __shared__ int sd[256];
    int b = blockIdx.x, t = threadIdx.x;
    int base = b * 1024;
    int v[4]; int s = 0;
#pragma unroll
    for (int j = 0; j < 4; ++j) {
        int idx = base + t * 4 + j;
        v[j] = (idx < N) ? cnt[idx] : 0;
        s += v[j];
    }
    sd[t] = s;
    __syncthreads();
    for (int off = 1; off < 256; off <<= 1) {
        int x = (t >= off) ? sd[t - off] : 0;
        __syncthreads();
        sd[t] += x;
        __syncthreads();
    }
    int off0 = bsum[b] + ((t == 0) ? 0 : sd[t - 1]);
#pragma unroll
    for (int j = 0; j < 4; ++j) {
        int idx = base + t * 4 + j;
        if (idx < N) { row_ptr[idx] = off0; cursor[idx] = off0; off0 += v[j]; }
    }
    if (b == 0 && t == 0) row_ptr[N] = E;
}

// packed scatter: ONE 8B store per edge (col | val-bits)
__global__ void scatter_kernel(const int* __restrict__ rows, const int* __restrict__ cols,
                               const float* __restrict__ vals, int* __restrict__ cursor,
                               uint2* __restrict__ edge_s, int E)
{
    int i = blockIdx.x * blockDim.x + threadIdx.x;
    if (i < E) {
        int r = rows[i];
        uint2 e;
        e.x = (unsigned)cols[i];
        e.y = __float_as_uint(vals[i]);
        int p = atomicAdd(&cursor[r], 1);
        edge_s[p] = e;
    }
}

// ---------------- gather SpMM ----------------
// one wave per destination row; lane holds 2 columns; fp32 accum; unroll-4
__global__ __launch_bounds__(256)
void spmm_gather(const int* __restrict__ row_ptr, const uint2* __restrict__ edge_s,
                 const _Float16* __restrict__ h, _Float16* __restrict__ temp, int N)
{
    int wave = threadIdx.x >> 6;
    int lane = threadIdx.x & 63;
    int row  = blockIdx.x * 4 + wave;
    if (row >= N) return;
    int s = __builtin_amdgcn_readfirstlane(row_ptr[row]);
    int e = __builtin_amdgcn_readfirstlane(row_ptr[row + 1]);
    float acc0 = 0.f, acc1 = 0.f;
    int i = s;
    for (; i + 3 < e; i += 4) {
        uint2 e0 = edge_s[i], e1 = edge_s[i + 1], e2 = edge_s[i + 2], e3 = edge_s[i + 3];
        half2v v0 = *(const half2v*)(h + (size_t)e0.x * 128 + lane * 2);
        half2v v1 = *(const half2v*)(h + (size_t)e1.x * 128 + lane * 2);
        half2v v2 = *(const half2v*)(h + (size_t)e2.x * 128 + lane * 2);
        half2v v3 = *(const half2v*)(h + (size_t)e3.x * 128 + lane * 2);
        float a0 = __uint_as_float(e0.y), a1 = __uint_as_float(e1.y);
        float a2 = __uint_as_float(e2.y), a3 = __uint_as_float(e3.y);
        acc0 += a0 * (float)v0[0]; acc1 += a0 * (float)v0[1];
        acc0 += a1 * (float)v1[0]; acc1 += a1 * (float)v1[1];
        acc0 += a2 * (float)v2[0]; acc1 += a2 * (float)v2[1];
        acc0 += a3 * (float)v3[0]; acc1 += a3 * (float)v3[1];
    }
    for (; i < e; ++i) {
        uint2 e0 = edge_s[i];
        half2v v0 = *(const half2v*)(h + (size_t)e0.x * 128 + lane * 2);
        float a0 = __uint_as_float(e0.y);
        acc0 += a0 * (float)v0[0]; acc1 += a0 * (float)v0[1];
    }
    half2v o = { (_Float16)acc0, (_Float16)acc1 };
    *(half2v*)(temp + (size_t)row * 128 + lane * 2) = o;
}

// ---------------- launcher ----------------
static inline size_t align256(size_t x) { return (x + 255) & ~(size_t)255; }

extern "C" void kernel_launch(void* const* d_in, const int* in_sizes, int n_in,
                              void* d_out, int out_size, void* d_ws, size_t ws_size,
                              hipStream_t stream)
{
    const float* AX        = (const float*)d_in[0];
    const int*   A_row     = (const int*)  d_in[1];
    const int*   A_col     = (const int*)  d_in[2];
    const float* A_val     = (const float*)d_in[3];
    const float* Wr_w      = (const float*)d_in[4];
    const float* Wr_b      = (const float*)d_in[5];
    const float* W_w       = (const float*)d_in[6];
    const float* W_b       = (const float*)d_in[7];
    const float* g_alpha   = (const float*)d_in[8];
    const float* act_alpha = (const float*)d_in[9];

    const int N = in_sizes[0] / 128;
    const int E = in_sizes[1];

    char* ws = (char*)d_ws;
    size_t off = 0;
    _Float16* h      = (_Float16*)(ws + off); off += align256((size_t)N * 128 * 2);
    _Float16* temp   = (_Float16*)(ws + off); off += align256((size_t)N * 128 * 2);
    uint2*    edge_s = (uint2*)   (ws + off); off += align256((size_t)E * 8);
    int*      cnt    = (int*)     (ws + off); off += align256((size_t)N * 4);
    int*      cursor = (int*)     (ws + off); off += align256((size_t)N * 4);
    int*      row_ptr= (int*)     (ws + off); off += align256((size_t)(N + 1) * 4);
    int*      bsum   = (int*)     (ws + off); off += align256(1024 * 4);
    (void)ws_size; (void)n_in; (void)out_size;

    const int gemm_grid = (N + 127) / 128;
    const int nb        = (N + 1023) / 1024;

    gemm128_prelu<true, true><<<gemm_grid, 256, 0, stream>>>(AX, Wr_w, Wr_b, g_alpha, h, N);

    hipMemsetAsync(cnt, 0, (size_t)N * 4, stream);
    hist_kernel<<<(E + 255) / 256, 256, 0, stream>>>(A_row, cnt, E);
    scan_block_sums<<<nb, 256, 0, stream>>>(cnt, bsum, N);
    scan_offsets<<<1, 128, 0, stream>>>(bsum, nb);
    scan_write<<<nb, 256, 0, stream>>>(cnt, bsum, row_ptr, cursor, N, E);
    scatter_kernel<<<(E + 255) / 256, 256, 0, stream>>>(A_row, A_col, A_val, cursor, edge_s, E);

    spmm_gather<<<(N + 3) / 4, 256, 0, stream>>>(row_ptr, edge_s, h, temp, N);

    gemm128_prelu<false, false><<<gemm_grid, 256, 0, stream>>>(temp, W_w, W_b, act_alpha, d_out, N);
}